// Round 9
// baseline (876.815 us; speedup 1.0000x reference)
//
#include <hip/hip_runtime.h>
#include <hip/hip_bf16.h>
#include <cstdint>
#include <cstddef>

#define EPSV 1e-5f
typedef unsigned short u16;
using short8 = __attribute__((ext_vector_type(8))) short;
using f32x4  = __attribute__((ext_vector_type(4))) float;

typedef __attribute__((address_space(1))) void* gp1;
typedef __attribute__((address_space(3))) void* lp3;

__device__ __forceinline__ void gload16(const void* g, void* l) {
    __builtin_amdgcn_global_load_lds((gp1)(void*)g, (lp3)l, 16, 0, 0);
}
__device__ __forceinline__ u16 f2bf(float v) {
    __hip_bfloat16 h = __float2bfloat16(v);
    return *reinterpret_cast<u16*>(&h);
}
__device__ __forceinline__ float bf2f(u16 u) {
    __hip_bfloat16 h; *reinterpret_cast<u16*>(&h) = u;
    return __bfloat162float(h);
}

// ============ ring zero: zero the 1-px border of padded NHWC bf16 planes ============
template<int PH2, int PW2, int C>
__global__ __launch_bounds__(256) void ring_kernel(u16* __restrict__ bh, u16* __restrict__ bl)
{
    constexpr int RN = 2 * PW2 + 2 * (PH2 - 2);
    constexpr int C8 = C / 8;
    int id = blockIdx.x * 256 + (int)threadIdx.x;
    if (id >= 512 * RN * C8) return;
    int c8 = id % C8; int t = id / C8;
    int rp = t % RN;  int im = t / RN;
    int py, px;
    if (rp < PW2)            { py = 0;       px = rp; }
    else if (rp < 2 * PW2)   { py = PH2 - 1; px = rp - PW2; }
    else { int rr = rp - 2 * PW2; py = 1 + (rr >> 1); px = (rr & 1) ? (PW2 - 1) : 0; }
    size_t off = ((size_t)(im * PH2 + py) * PW2 + px) * C + c8 * 8;
    uint4 z = {0u, 0u, 0u, 0u};
    *(uint4*)(bh + off) = z;
    *(uint4*)(bl + off) = z;
}

// ============ weight prep: fold BN scale, transpose to [9][Cout][Cin], split bf16 ============
template<int CIN, int COUT>
__global__ __launch_bounds__(256) void wprep_kernel(
    const float* __restrict__ w, const float* __restrict__ b,
    const float* __restrict__ g, const float* __restrict__ bt,
    const float* __restrict__ rm, const float* __restrict__ rv,
    u16* __restrict__ WH, u16* __restrict__ WL, float* __restrict__ bias)
{
    int id = blockIdx.x * 256 + (int)threadIdx.x;
    if (id >= CIN * COUT) return;
    int co = id / CIN, ci = id % CIN;
    float s = g[co] / sqrtf(rv[co] + EPSV);
    #pragma unroll
    for (int k = 0; k < 9; ++k) {
        float v = w[((size_t)co * CIN + ci) * 9 + k] * s;
        u16 hh = f2bf(v);
        size_t o = ((size_t)k * COUT + co) * CIN + ci;
        WH[o] = hh;
        WL[o] = f2bf(v - bf2f(hh));
    }
    if (ci == 0) bias[co] = (b[co] - rm[co]) * s + bt[co];
}

// ============ conv0: 3->32, fp32 vector math, out = padded NHWC split-bf16 ============
__global__ __launch_bounds__(256) void conv0_kernel(
    const float* __restrict__ x, const float* __restrict__ w,
    const float* __restrict__ bias, const float* __restrict__ g,
    const float* __restrict__ bt, const float* __restrict__ rm,
    const float* __restrict__ rv, u16* __restrict__ Oh, u16* __restrict__ Ol)
{
    const int blk = blockIdx.x;            // 2048 blocks
    const int img = blk >> 2;
    const int p = ((blk & 3) << 8) | (int)threadIdx.x;   // pixel 0..1023
    const int y = p >> 5, xx = p & 31;
    const float* xin = x + (size_t)img * 3 * 1024;
    float xv[3][9];
    #pragma unroll
    for (int ci = 0; ci < 3; ++ci)
      #pragma unroll
      for (int ky = 0; ky < 3; ++ky)
        #pragma unroll
        for (int kx = 0; kx < 3; ++kx) {
            int yy = y + ky - 1, xc = xx + kx - 1;
            bool v = (yy >= 0) && (yy < 32) && (xc >= 0) && (xc < 32);
            xv[ci][ky * 3 + kx] = v ? xin[ci * 1024 + yy * 32 + xc] : 0.0f;
        }
    union { u16 u[32]; uint4 v4[4]; } oh, ol;
    #pragma unroll
    for (int co = 0; co < 32; ++co) {
        float s = g[co] / sqrtf(rv[co] + EPSV);
        float c = (bias[co] - rm[co]) * s + bt[co];
        float acc = 0.f;
        #pragma unroll
        for (int ci = 0; ci < 3; ++ci)
          #pragma unroll
          for (int k = 0; k < 9; ++k)
            acc += w[(co * 3 + ci) * 9 + k] * xv[ci][k];
        float v = acc * s + c;
        v = v > 0.f ? v : 0.f;
        u16 hh = f2bf(v);
        oh.u[co] = hh;
        ol.u[co] = f2bf(v - bf2f(hh));
    }
    size_t po = ((size_t)(img * 34 + y + 1) * 34 + xx + 1) * 32;
    #pragma unroll
    for (int q = 0; q < 4; ++q) {
        ((uint4*)(Oh + po))[q] = oh.v4[q];
        ((uint4*)(Ol + po))[q] = ol.v4[q];
    }
}

// ============ MFMA conv: shift-and-GEMM, split-bf16, padded NHWC in/out ============
// R9 K-loop: B fragments global->register, DOUBLE-BUFFERED one sh step ahead
// (issue loads for sh+1, compute 48 MFMAs of sh, then use). No barrier between
// issue and use -> compiler emits fine-grained vmcnt(N) with ~233 cyc of MFMA
// covering L2 latency (fixes R8's load-at-use stall; avoids R7's barrier drain).
// Barriers: 2 per cb (A staging only). A LDS swizzle kept (conflicts=0, R6).
template<int CIN, int COUT, int H, int W, int BM, int BN, int MODE>
__global__ __launch_bounds__(256, 3) void convM_kernel(
    const u16* __restrict__ Ah, const u16* __restrict__ Al,
    const u16* __restrict__ Wh, const u16* __restrict__ Wl,
    const float* __restrict__ bias,
    u16* __restrict__ Oh, u16* __restrict__ Ol, float* __restrict__ featsPart)
{
    constexpr int KC = CIN / 32;
    constexpr int ROWS = BM / W;
    constexpr int WM = BM / 64;
    constexpr int PW = W + 2;
    constexpr int AT = (ROWS + 2) * PW;
    constexpr int ACH = AT * 4;
    constexpr int LW2 = (W == 32) ? 5 : 4;
    constexpr int MPI = (H * W) / BM;

    __shared__ u16 lA[2][AT * 32];

    const int tid = (int)threadIdx.x;
    const int lane = tid & 63;
    const int wv = tid >> 6;
    const int wm = (WM == 4) ? wv : (wv >> 1);
    const int wn = (WM == 4) ? 0 : (wv & 1);
    const int l15 = lane & 15, quad = lane >> 4;

    const int mblk = (int)blockIdx.x, nblk = (int)blockIdx.y;
    const int img = mblk / MPI;
    const int y0 = (mblk % MPI) * ROWS;
    const size_t imgRow = (size_t)img * (H + 2);

    // per-lane B fragment base (u16 units): row = n-index, cols = quad*8..+8
    const u16* wbh = Wh + (size_t)(nblk * BN + wn * 64 + l15) * CIN + quad * 8;
    const u16* wbl = Wl + (size_t)(nblk * BN + wn * 64 + l15) * CIN + quad * 8;

    f32x4 acc[4][4];
    f32x4 zz = {0.f, 0.f, 0.f, 0.f};
    #pragma unroll
    for (int i = 0; i < 4; ++i)
      #pragma unroll
      for (int j = 0; j < 4; ++j) acc[i][j] = zz;

    short8 Bh[2][4], Bl[2][4];              // [slot][nt]
    auto loadB = [&](int cbg, int shg, int slot) {
        const size_t woff = (size_t)shg * COUT * CIN + cbg * 32;
        #pragma unroll
        for (int nt = 0; nt < 4; ++nt) {
            Bh[slot][nt] = *(const short8*)&wbh[woff + (size_t)nt * 16 * CIN];
            Bl[slot][nt] = *(const short8*)&wbl[woff + (size_t)nt * 16 * CIN];
        }
    };

    // A staging (swizzle: 16B chunk q of 64B line p at slot (q+(p>>1))&3)
    auto stageA = [&](int cb) {
        #pragma unroll
        for (int it = 0; it < (ACH + 255) / 256; ++it) {
            int id = it * 256 + tid;
            if (id < ACH) {
                int p = id >> 2;
                int s = ((id & 3) - (p >> 1)) & 3;
                int yy = p / PW, xx = p - yy * PW;
                size_t ge = ((imgRow + y0 + yy) * PW + xx) * CIN + cb * 32 + s * 8;
                u16* ld = (u16*)&lA[0][0] + (size_t)(it * 256 + wv * 64) * 8;
                gload16(Ah + ge, ld);
                gload16(Al + ge, ld + AT * 32);
            }
        }
    };

    loadB(0, 0, 0);                         // invariant: slot 0 holds (cb, 0)
    for (int cb = 0; cb < KC; ++cb) {
        if (cb) __syncthreads();            // prev readers of lA done
        stageA(cb);
        __syncthreads();                    // staged tile landed
        #pragma unroll
        for (int sh = 0; sh < 9; ++sh) {
            const int cur = sh & 1, nxt = (sh + 1) & 1;
            if (sh < 8) loadB(cb, sh + 1, nxt);
            else if (cb + 1 < KC) loadB(cb + 1, 0, nxt);
            const int ky = sh / 3, kx = sh - 3 * (sh / 3);
            #pragma unroll
            for (int mt = 0; mt < 4; ++mt) {
                int p = wm * 64 + mt * 16 + l15;
                int yl = p >> LW2, xl = p & (W - 1);
                int pix = (yl + ky) * PW + xl + kx;
                int aoff = pix * 32 + (((quad + (pix >> 1)) & 3) * 8);
                short8 ah = *(const short8*)&lA[0][aoff];
                short8 al = *(const short8*)&lA[1][aoff];
                #pragma unroll
                for (int nt = 0; nt < 4; ++nt) {
                    acc[mt][nt] = __builtin_amdgcn_mfma_f32_16x16x32_bf16(ah, Bh[cur][nt], acc[mt][nt], 0, 0, 0);
                    acc[mt][nt] = __builtin_amdgcn_mfma_f32_16x16x32_bf16(ah, Bl[cur][nt], acc[mt][nt], 0, 0, 0);
                    acc[mt][nt] = __builtin_amdgcn_mfma_f32_16x16x32_bf16(al, Bh[cur][nt], acc[mt][nt], 0, 0, 0);
                }
            }
        }
        if (cb + 1 < KC) {                  // restore parity: (cb+1,0) -> slot 0
            #pragma unroll
            for (int nt = 0; nt < 4; ++nt) { Bh[0][nt] = Bh[1][nt]; Bl[0][nt] = Bl[1][nt]; }
        }
    }

    if constexpr (MODE == 0) {
        #pragma unroll
        for (int mt = 0; mt < 4; ++mt) {
            int pbase = wm * 64 + mt * 16 + quad * 4;
            int yy = pbase >> LW2;
            #pragma unroll
            for (int nt = 0; nt < 4; ++nt) {
                int n = nblk * BN + wn * 64 + nt * 16 + l15;
                float bs = bias[n];
                #pragma unroll
                for (int r = 0; r < 4; ++r) {
                    int xx = (pbase & (W - 1)) + r;
                    float v = acc[mt][nt][r] + bs; v = v > 0.f ? v : 0.f;
                    size_t oo = ((size_t)(img * (H + 2) + y0 + yy + 1) * (W + 2) + xx + 1) * COUT + n;
                    u16 hh = f2bf(v);
                    Oh[oo] = hh;
                    Ol[oo] = f2bf(v - bf2f(hh));
                }
            }
        }
    } else if constexpr (MODE == 1) {
        #pragma unroll
        for (int nt = 0; nt < 4; ++nt) {
            int n = nt * 16 + l15;
            float bs = bias[n];
            #pragma unroll
            for (int mb = 0; mb < 2; ++mb) {
                #pragma unroll
                for (int xp = 0; xp < 2; ++xp) {
                    float v = fmaxf(fmaxf(acc[mb][nt][2 * xp], acc[mb][nt][2 * xp + 1]),
                                    fmaxf(acc[mb + 2][nt][2 * xp], acc[mb + 2][nt][2 * xp + 1]));
                    v += bs; v = v > 0.f ? v : 0.f;
                    int py = (y0 >> 1) + wm;
                    int px = mb * 8 + quad * 2 + xp;
                    size_t oo = ((size_t)(img * 18 + py + 1) * 18 + px + 1) * COUT + n;
                    u16 hh = f2bf(v);
                    Oh[oo] = hh;
                    Ol[oo] = f2bf(v - bf2f(hh));
                }
            }
        }
    } else {
        __shared__ float fbuf[2][128];
        #pragma unroll
        for (int nt = 0; nt < 4; ++nt) {
            float bs = bias[nblk * BN + wn * 64 + nt * 16 + l15];
            float s = 0.f;
            #pragma unroll
            for (int mp = 0; mp < 2; ++mp)
              #pragma unroll
              for (int xp = 0; xp < 2; ++xp) {
                  float v = fmaxf(fmaxf(acc[2 * mp][nt][2 * xp], acc[2 * mp][nt][2 * xp + 1]),
                                  fmaxf(acc[2 * mp + 1][nt][2 * xp], acc[2 * mp + 1][nt][2 * xp + 1]));
                  v += bs; v = v > 0.f ? v : 0.f;
                  s += v;
              }
            s += __shfl_xor(s, 16, 64);
            s += __shfl_xor(s, 32, 64);
            if (quad == 0) fbuf[wm][wn * 64 + nt * 16 + l15] = s;
        }
        __syncthreads();
        if (tid < 128) {
            float f = (fbuf[0][tid] + fbuf[1][tid]) * (1.0f / 64.0f);
            featsPart[((size_t)(mblk % MPI) * 512 + img) * 256 + nblk * BN + tid] = f;
        }
    }
}

// ============== head GEMM + log-softmax + conf ==============
__global__ __launch_bounds__(128) void head_kernel(
    const float* __restrict__ featsPart, const float* __restrict__ cls_w,
    const float* __restrict__ cls_b, float* __restrict__ logits,
    float* __restrict__ conf)
{
    __shared__ float f[256];
    __shared__ float wt[80 * 65];
    __shared__ float lg[80];
    const int b = blockIdx.x, tid = (int)threadIdx.x;
    f[tid]       = featsPart[b * 256 + tid]       + featsPart[131072 + b * 256 + tid];
    f[tid + 128] = featsPart[b * 256 + tid + 128] + featsPart[131072 + b * 256 + tid + 128];
    float acc = 0.f;
    for (int ch = 0; ch < 4; ++ch) {
        __syncthreads();
        for (int q = tid; q < 80 * 64; q += 128) {
            int r = q >> 6, cc = q & 63;
            wt[r * 65 + cc] = cls_w[r * 256 + ch * 64 + cc];
        }
        __syncthreads();
        if (tid < 80) {
            #pragma unroll 8
            for (int dd = 0; dd < 64; ++dd)
                acc += wt[tid * 65 + dd] * f[ch * 64 + dd];
        }
    }
    if (tid < 80) {
        acc += cls_b[tid];
        logits[b * 80 + tid] = acc;
        lg[tid] = acc;
    }
    __syncthreads();
    if (tid < 80 && (tid % 10) == 0) {
        const int e = tid / 10;
        float m = lg[e * 10];
        for (int cc = 1; cc < 10; ++cc) m = fmaxf(m, lg[e * 10 + cc]);
        float ssum = 0.f;
        for (int cc = 0; cc < 10; ++cc) ssum += expf(lg[e * 10 + cc] - m);
        float lz = m + logf(ssum);
        float cf = 0.f;
        for (int cc = 0; cc < 10; ++cc) {
            float lp = lg[e * 10 + cc] - lz;
            cf += expf(lp) * lp;
        }
        conf[b * 8 + e] = cf;
    }
}

// ======= presort: per-expert descending sort of conf (done ONCE) =======
__global__ __launch_bounds__(256) void presort_kernel(
    const float* __restrict__ confG, u16* __restrict__ sidx0)
{
    __shared__ float v[512];
    __shared__ u16 bi[512];
    const int j = (int)blockIdx.x, tid = (int)threadIdx.x;
    for (int r = tid; r < 512; r += 256) { v[r] = confG[r * 8 + j]; bi[r] = (u16)r; }
    for (int k = 2; k <= 512; k <<= 1)
        for (int jj = k >> 1; jj > 0; jj >>= 1) {
            __syncthreads();
            int i = ((tid & ~(jj - 1)) << 1) | (tid & (jj - 1));
            int p = i | jj;
            float va = v[i], vb = v[p];
            u16 ia = bi[i], ib = bi[p];
            bool first = (va > vb) || (va == vb && ia < ib);
            bool up = (i & k) == 0;
            if (up ? !first : first) { v[i] = vb; v[p] = va; bi[i] = ib; bi[p] = ia; }
        }
    __syncthreads();
    for (int r = tid; r < 512; r += 256)
        sidx0[j * 512 + r] = (u16)(bi[r] * 8 + j);
}

// ======= routing: per cycle [rescale -> 3-level merge-path -> greedy scan] + final =======
__global__ __launch_bounds__(1024) void route_kernel(
    const float* __restrict__ confG,   // [512*8]
    const float* __restrict__ logitsG, // [512*80]
    const u16*   __restrict__ sidx0,   // [4096] presorted per-expert idx lists
    float* __restrict__ outv)          // [5120 final | 4096 conf | 4096 D]
{
    __shared__ float valById[4096];
    __shared__ float sv[4096];
    __shared__ u16 P[4096];
    __shared__ u16 mA[4096];
    __shared__ u16 mB[4096];
    __shared__ unsigned char Dls[512];
    __shared__ int ec[8];
    __shared__ int assignedS;
    const int tid = (int)threadIdx.x;

    for (int t = tid; t < 4096; t += 1024) {
        valById[t] = confG[t];
        P[t] = sidx0[t];
    }
    if (tid < 512) Dls[tid] = 0;
    if (tid < 8) ec[tid] = 0;
    if (tid == 0) assignedS = 0;

    auto earlier = [&](u16 a, u16 b) -> bool {
        float va = sv[a], vb = sv[b];
        return (va > vb) || (va == vb && a < b);
    };
    auto mergeChunk = [&](const u16* X, const u16* Y, int n, int o0, u16* out) {
        int lo = o0 - n; if (lo < 0) lo = 0;
        int hi = o0 < n ? o0 : n;
        while (lo < hi) {
            int mid = (lo + hi) >> 1;
            if (earlier(X[mid], Y[o0 - 1 - mid])) lo = mid + 1; else hi = mid;
        }
        int i = lo, jj = o0 - lo;
        #pragma unroll
        for (int q = 0; q < 4; ++q) {
            u16 xc = X[i < n ? i : (n - 1)];
            u16 yc = Y[jj < n ? jj : (n - 1)];
            bool takeX = (jj >= n) || ((i < n) && earlier(xc, yc));
            out[q] = takeX ? xc : yc;
            if (takeX) ++i; else ++jj;
        }
    };

    for (int cycle = 0; cycle < 4; ++cycle) {
        __syncthreads();
        for (int t = tid; t < 4096; t += 1024) {
            float sc = 1.0f - ((float)ec[t & 7]) / 160.0f;
            sv[t] = valById[t] * sc;
        }
        __syncthreads();
        {   // L1: P (8 lists of 512) -> mA (4 lists of 1024)
            int g = tid << 2;
            int p = g >> 10, o0 = g & 1023;
            mergeChunk(&P[(p << 1) * 512], &P[(p << 1) * 512 + 512], 512, o0, &mA[(p << 10) + o0]);
        }
        __syncthreads();
        {   // L2: mA -> mB (2 lists of 2048)
            int g = tid << 2;
            int p = g >> 11, o0 = g & 2047;
            mergeChunk(&mA[p << 11], &mA[(p << 11) + 1024], 1024, o0, &mB[(p << 11) + o0]);
        }
        __syncthreads();
        {   // L3: mB -> mA (full 4096 order, descending)
            int o0 = tid << 2;
            mergeChunk(&mB[0], &mB[2048], 2048, o0, &mA[o0]);
        }
        __syncthreads();
        if (tid < 64) {
            const int lane = tid;
            int cyc = 0;
            int assigned = assignedS;
            for (int chunk = 0; chunk < 64; ++chunk) {
                if (cyc >= 256 || assigned >= 1024) break;
                int id = mA[(chunk << 6) | lane];
                int b = id >> 3, j = id & 7;
                unsigned d = Dls[b];
                bool notA = ((d >> j) & 1) == 0;
                int ecj = ec[j];
                int scb = __popc(d & 255);
                unsigned long long sb = ~0ull;
                #pragma unroll
                for (int t2 = 0; t2 < 9; ++t2) {
                    unsigned long long bl = __ballot((b >> t2) & 1);
                    sb &= ((b >> t2) & 1) ? bl : ~bl;
                }
                unsigned long long jb0 = __ballot(j & 1);
                unsigned long long jb1 = __ballot((j >> 1) & 1);
                unsigned long long jb2 = __ballot((j >> 2) & 1);
                unsigned long long sj = ((j & 1) ? jb0 : ~jb0) &
                                        ((j & 2) ? jb1 : ~jb1) &
                                        ((j & 4) ? jb2 : ~jb2);
                unsigned long long earlierM = (1ull << lane) - 1ull;
                bool ok = notA && (ecj < 160) && (scb < 2);
                unsigned long long okm = __ballot(ok);
                for (int it = 0; it < 64; ++it) {
                    unsigned long long em = okm & earlierM;
                    int aE = __popcll(em & sj);
                    int aS = __popcll(em & sb);
                    int aC = __popcll(em);
                    bool ok2 = notA && (ecj + aE) < 160 && (scb + aS) < 2 &&
                               (cyc + aC) < 256 && (assigned + aC) < 1024;
                    unsigned long long okm2 = __ballot(ok2);
                    ok = ok2;
                    if (okm2 == okm) break;
                    okm = okm2;
                }
                int add = __popcll(okm);
                if (lane < 8) {
                    unsigned long long mj = ((lane & 1) ? jb0 : ~jb0) &
                                            ((lane & 2) ? jb1 : ~jb1) &
                                            ((lane & 4) ? jb2 : ~jb2);
                    int c2 = __popcll(mj & okm);
                    if (c2) ec[lane] += c2;
                }
                if (ok) {
                    unsigned long long grp = okm & sb;
                    if (lane == __builtin_ctzll(grp)) {
                        unsigned orb = 0;
                        #pragma unroll
                        for (int jj2 = 0; jj2 < 8; ++jj2) {
                            unsigned long long mj2 = ((jj2 & 1) ? jb0 : ~jb0) &
                                                     ((jj2 & 2) ? jb1 : ~jb1) &
                                                     ((jj2 & 4) ? jb2 : ~jb2);
                            if (mj2 & grp) orb |= (1u << jj2);
                        }
                        Dls[b] = (unsigned char)(d | orb);
                    }
                }
                cyc += add;
                assigned += add;
                __threadfence_block();
            }
            if (lane == 0) assignedS = assigned;
        }
    }
    __syncthreads();

    for (int o = tid; o < 5120; o += 1024) {
        int b = o / 10, c = o - b * 10;
        unsigned d = Dls[b];
        float norm = fmaxf((float)__popc(d & 255), 1.0f);
        float sum = 0.f;
        #pragma unroll
        for (int e = 0; e < 8; ++e)
            if ((d >> e) & 1)
                sum += confG[b * 8 + e] * logitsG[(b * 8 + e) * 10 + c];
        outv[o] = sum / norm;
    }
    for (int t = tid; t < 4096; t += 1024) {
        outv[5120 + t] = confG[t];
        outv[9216 + t] = (float)((Dls[t >> 3] >> (t & 7)) & 1);
    }
}

// ============================ launch ============================
extern "C" void kernel_launch(void* const* d_in, const int* in_sizes, int n_in,
                              void* d_out, int out_size, void* d_ws, size_t ws_size,
                              hipStream_t stream)
{
    const float* x    = (const float*)d_in[0];
    const float* w0   = (const float*)d_in[1];
    const float* b0   = (const float*)d_in[2];
    const float* g0   = (const float*)d_in[3];
    const float* bt0  = (const float*)d_in[4];
    const float* rm0  = (const float*)d_in[5];
    const float* rv0  = (const float*)d_in[6];
    const float* w1   = (const float*)d_in[7];
    const float* b1   = (const float*)d_in[8];
    const float* g1   = (const float*)d_in[9];
    const float* bt1  = (const float*)d_in[10];
    const float* rm1  = (const float*)d_in[11];
    const float* rv1  = (const float*)d_in[12];
    const float* w2   = (const float*)d_in[13];
    const float* b2   = (const float*)d_in[14];
    const float* g2   = (const float*)d_in[15];
    const float* bt2  = (const float*)d_in[16];
    const float* rm2  = (const float*)d_in[17];
    const float* rv2  = (const float*)d_in[18];
    const float* w3   = (const float*)d_in[19];
    const float* b3   = (const float*)d_in[20];
    const float* g3   = (const float*)d_in[21];
    const float* bt3  = (const float*)d_in[22];
    const float* rm3  = (const float*)d_in[23];
    const float* rv3  = (const float*)d_in[24];
    const float* cls_w = (const float*)d_in[25];
    const float* cls_b = (const float*)d_in[26];
    float* outp = (float*)d_out;

    char* ws = (char*)d_ws;
    u16* A1H = (u16*)(ws);
    u16* A1L = (u16*)(ws + 21233664);
    u16* A0H = (u16*)(ws + 42467328);
    u16* A0L = (u16*)(ws + 42467328 + 37879808);
    u16* A2H = (u16*)(ws + 42467328);
    u16* A2L = (u16*)(ws + 42467328 + 42467328);
    u16* W1H = (u16*)(ws + 127401984);
    u16* W1L = (u16*)(ws + 127438848);
    u16* W2H = (u16*)(ws + 127475712);
    u16* W2L = (u16*)(ws + 127623168);
    u16* W3H = (u16*)(ws + 127770624);
    u16* W3L = (u16*)(ws + 128360448);
    float* BS1 = (float*)(ws + 128950272);
    float* BS2 = (float*)(ws + 128950528);
    float* BS3 = (float*)(ws + 128951040);
    float* featsPart = (float*)(ws + 128952064);   // [2][512][256]
    float* logits    = (float*)(ws + 130000640);
    float* conf      = (float*)(ws + 130164480);
    u16* sidx0 = (u16*)(ws + 42467328);            // dead-after-conv3 region

    ring_kernel<34, 34, 32><<<(512 * 132 * 4 + 255) / 256, 256, 0, stream>>>(A0H, A0L);
    ring_kernel<18, 18, 64><<<(512 * 68 * 8 + 255) / 256, 256, 0, stream>>>(A1H, A1L);
    wprep_kernel<32, 64><<<8, 256, 0, stream>>>(w1, b1, g1, bt1, rm1, rv1, W1H, W1L, BS1);
    wprep_kernel<64, 128><<<32, 256, 0, stream>>>(w2, b2, g2, bt2, rm2, rv2, W2H, W2L, BS2);
    wprep_kernel<128, 256><<<128, 256, 0, stream>>>(w3, b3, g3, bt3, rm3, rv3, W3H, W3L, BS3);

    conv0_kernel<<<2048, 256, 0, stream>>>(x, w0, b0, g0, bt0, rm0, rv0, A0H, A0L);
    convM_kernel<32, 64, 32, 32, 256, 64, 1>
        <<<dim3(2048, 1), 256, 0, stream>>>(A0H, A0L, W1H, W1L, BS1, A1H, A1L, nullptr);
    ring_kernel<18, 18, 128><<<(512 * 68 * 16 + 255) / 256, 256, 0, stream>>>(A2H, A2L);
    convM_kernel<64, 128, 16, 16, 128, 128, 0>
        <<<dim3(1024, 1), 256, 0, stream>>>(A1H, A1L, W2H, W2L, BS2, A2H, A2L, nullptr);
    convM_kernel<128, 256, 16, 16, 128, 128, 2>
        <<<dim3(1024, 2), 256, 0, stream>>>(A2H, A2L, W3H, W3L, BS3, nullptr, nullptr, featsPart);
    head_kernel<<<512, 128, 0, stream>>>(featsPart, cls_w, cls_b, logits, conf);
    presort_kernel<<<8, 256, 0, stream>>>(conf, sidx0);
    route_kernel<<<1, 1024, 0, stream>>>(conf, logits, sidx0, outp);
}

// Round 10
// 623.260 us; speedup vs baseline: 1.4068x; 1.4068x over previous
//
#include <hip/hip_runtime.h>
#include <hip/hip_bf16.h>
#include <cstdint>
#include <cstddef>

#define EPSV 1e-5f
typedef unsigned short u16;
using short8 = __attribute__((ext_vector_type(8))) short;
using f32x4  = __attribute__((ext_vector_type(4))) float;

typedef __attribute__((address_space(1))) void* gp1;
typedef __attribute__((address_space(3))) void* lp3;

__device__ __forceinline__ void gload16(const void* g, void* l) {
    __builtin_amdgcn_global_load_lds((gp1)(void*)g, (lp3)l, 16, 0, 0);
}
__device__ __forceinline__ u16 f2bf(float v) {
    __hip_bfloat16 h = __float2bfloat16(v);
    return *reinterpret_cast<u16*>(&h);
}
__device__ __forceinline__ float bf2f(u16 u) {
    __hip_bfloat16 h; *reinterpret_cast<u16*>(&h) = u;
    return __bfloat162float(h);
}

// ============ ring zero: zero the 1-px border of padded NHWC bf16 planes ============
template<int PH2, int PW2, int C>
__global__ __launch_bounds__(256) void ring_kernel(u16* __restrict__ bh, u16* __restrict__ bl)
{
    constexpr int RN = 2 * PW2 + 2 * (PH2 - 2);
    constexpr int C8 = C / 8;
    int id = blockIdx.x * 256 + (int)threadIdx.x;
    if (id >= 512 * RN * C8) return;
    int c8 = id % C8; int t = id / C8;
    int rp = t % RN;  int im = t / RN;
    int py, px;
    if (rp < PW2)            { py = 0;       px = rp; }
    else if (rp < 2 * PW2)   { py = PH2 - 1; px = rp - PW2; }
    else { int rr = rp - 2 * PW2; py = 1 + (rr >> 1); px = (rr & 1) ? (PW2 - 1) : 0; }
    size_t off = ((size_t)(im * PH2 + py) * PW2 + px) * C + c8 * 8;
    uint4 z = {0u, 0u, 0u, 0u};
    *(uint4*)(bh + off) = z;
    *(uint4*)(bl + off) = z;
}

// ============ weight prep: fold BN scale, transpose to [9][Cout][Cin], split bf16 ============
template<int CIN, int COUT>
__global__ __launch_bounds__(256) void wprep_kernel(
    const float* __restrict__ w, const float* __restrict__ b,
    const float* __restrict__ g, const float* __restrict__ bt,
    const float* __restrict__ rm, const float* __restrict__ rv,
    u16* __restrict__ WH, u16* __restrict__ WL, float* __restrict__ bias)
{
    int id = blockIdx.x * 256 + (int)threadIdx.x;
    if (id >= CIN * COUT) return;
    int co = id / CIN, ci = id % CIN;
    float s = g[co] / sqrtf(rv[co] + EPSV);
    #pragma unroll
    for (int k = 0; k < 9; ++k) {
        float v = w[((size_t)co * CIN + ci) * 9 + k] * s;
        u16 hh = f2bf(v);
        size_t o = ((size_t)k * COUT + co) * CIN + ci;
        WH[o] = hh;
        WL[o] = f2bf(v - bf2f(hh));
    }
    if (ci == 0) bias[co] = (b[co] - rm[co]) * s + bt[co];
}

// ============ conv0: 3->32, fp32 vector math, out = padded NHWC split-bf16 ============
__global__ __launch_bounds__(256) void conv0_kernel(
    const float* __restrict__ x, const float* __restrict__ w,
    const float* __restrict__ bias, const float* __restrict__ g,
    const float* __restrict__ bt, const float* __restrict__ rm,
    const float* __restrict__ rv, u16* __restrict__ Oh, u16* __restrict__ Ol)
{
    const int blk = blockIdx.x;            // 2048 blocks
    const int img = blk >> 2;
    const int p = ((blk & 3) << 8) | (int)threadIdx.x;   // pixel 0..1023
    const int y = p >> 5, xx = p & 31;
    const float* xin = x + (size_t)img * 3 * 1024;
    float xv[3][9];
    #pragma unroll
    for (int ci = 0; ci < 3; ++ci)
      #pragma unroll
      for (int ky = 0; ky < 3; ++ky)
        #pragma unroll
        for (int kx = 0; kx < 3; ++kx) {
            int yy = y + ky - 1, xc = xx + kx - 1;
            bool v = (yy >= 0) && (yy < 32) && (xc >= 0) && (xc < 32);
            xv[ci][ky * 3 + kx] = v ? xin[ci * 1024 + yy * 32 + xc] : 0.0f;
        }
    union { u16 u[32]; uint4 v4[4]; } oh, ol;
    #pragma unroll
    for (int co = 0; co < 32; ++co) {
        float s = g[co] / sqrtf(rv[co] + EPSV);
        float c = (bias[co] - rm[co]) * s + bt[co];
        float acc = 0.f;
        #pragma unroll
        for (int ci = 0; ci < 3; ++ci)
          #pragma unroll
          for (int k = 0; k < 9; ++k)
            acc += w[(co * 3 + ci) * 9 + k] * xv[ci][k];
        float v = acc * s + c;
        v = v > 0.f ? v : 0.f;
        u16 hh = f2bf(v);
        oh.u[co] = hh;
        ol.u[co] = f2bf(v - bf2f(hh));
    }
    size_t po = ((size_t)(img * 34 + y + 1) * 34 + xx + 1) * 32;
    #pragma unroll
    for (int q = 0; q < 4; ++q) {
        ((uint4*)(Oh + po))[q] = oh.v4[q];
        ((uint4*)(Ol + po))[q] = ol.v4[q];
    }
}

// ============ MFMA conv: shift-and-GEMM, split-bf16, padded NHWC in/out ============
// R10: K-loop is EXACT R6 (proven 192us conv3: per-sh B LDS staging, 2 barriers/sh,
// swizzle conflicts=0). New: BN=64 for the W=16 layers via 2x2 wave grid
// (wave = 64m x 32n, NT=2) -> lB 16.4->8 KB, LDS 40.4->31 KB -> 5 blocks/CU
// (was 1.7) so co-resident blocks hide the barrier drains (m114 overlap).
// conv1 (BM=256) derives NT=4/WN=1 -> bit-identical to R6.
template<int CIN, int COUT, int H, int W, int BM, int BN, int MODE>
__global__ __launch_bounds__(256, 2) void convM_kernel(
    const u16* __restrict__ Ah, const u16* __restrict__ Al,
    const u16* __restrict__ Wh, const u16* __restrict__ Wl,
    const float* __restrict__ bias,
    u16* __restrict__ Oh, u16* __restrict__ Ol, float* __restrict__ featsPart)
{
    constexpr int KC = CIN / 32;
    constexpr int ROWS = BM / W;
    constexpr int WM = BM / 64;             // wave-m groups (4 or 2)
    constexpr int WN = 4 / WM;              // wave-n groups (1 or 2)
    constexpr int NT = BN / (WN * 16);      // 16-wide n-frags per wave (4 or 2)
    constexpr int PW = W + 2;
    constexpr int AT = (ROWS + 2) * PW;
    constexpr int ACH = AT * 4;
    constexpr int BCH = BN * 4;
    constexpr int LW2 = (W == 32) ? 5 : 4;
    constexpr int MPI = (H * W) / BM;

    __shared__ u16 lA[2][AT * 32];
    __shared__ u16 lB[2][BN * 32];

    const int tid = (int)threadIdx.x;
    const int lane = tid & 63;
    const int wv = tid >> 6;
    const int wm = (WM == 4) ? wv : (wv >> 1);
    const int wn = (WM == 4) ? 0 : (wv & 1);
    const int l15 = lane & 15, quad = lane >> 4;

    const int mblk = (int)blockIdx.x, nblk = (int)blockIdx.y;
    const int img = mblk / MPI;
    const int y0 = (mblk % MPI) * ROWS;
    const size_t imgRow = (size_t)img * (H + 2);

    f32x4 acc[4][NT];
    f32x4 zz = {0.f, 0.f, 0.f, 0.f};
    #pragma unroll
    for (int i = 0; i < 4; ++i)
      #pragma unroll
      for (int j = 0; j < NT; ++j) acc[i][j] = zz;

    for (int cb = 0; cb < KC; ++cb) {
        __syncthreads();
        // ---- stage A halo tile, swizzled: 16B chunk q of 64B line p at slot (q+(p>>1))&3
        #pragma unroll
        for (int it = 0; it < (ACH + 255) / 256; ++it) {
            int id = it * 256 + tid;
            if (id < ACH) {
                int p = id >> 2;
                int s = ((id & 3) - (p >> 1)) & 3;
                int yy = p / PW, xx = p - yy * PW;
                size_t ge = ((imgRow + y0 + yy) * PW + xx) * CIN + cb * 32 + s * 8;
                u16* ld = (u16*)&lA[0][0] + (size_t)(it * 256 + wv * 64) * 8;
                gload16(Ah + ge, ld);
                gload16(Al + ge, ld + AT * 32);
            }
        }
        for (int sh = 0; sh < 9; ++sh) {
            const int ky = sh / 3, kx = sh - 3 * (sh / 3);
            if (sh) __syncthreads();
            // ---- stage B chunk, same swizzle over rows n
            #pragma unroll
            for (int it = 0; it < (BCH + 255) / 256; ++it) {
                int id = it * 256 + tid;
                if (id < BCH) {
                    int n = id >> 2;
                    int s = ((id & 3) - (n >> 1)) & 3;
                    size_t ge = ((size_t)sh * COUT + nblk * BN + n) * CIN + cb * 32 + s * 8;
                    u16* ld = (u16*)&lB[0][0] + (size_t)(it * 256 + wv * 64) * 8;
                    gload16(Wh + ge, ld);
                    gload16(Wl + ge, ld + BN * 32);
                }
            }
            __syncthreads();
            short8 bh[NT], bl[NT];
            #pragma unroll
            for (int nt = 0; nt < NT; ++nt) {
                int nrow = wn * (NT * 16) + nt * 16 + l15;
                int boff = nrow * 32 + (((quad + (nrow >> 1)) & 3) * 8);
                bh[nt] = *(const short8*)&lB[0][boff];
                bl[nt] = *(const short8*)&lB[1][boff];
            }
            #pragma unroll
            for (int mt = 0; mt < 4; ++mt) {
                int p = wm * 64 + mt * 16 + l15;
                int yl = p >> LW2, xl = p & (W - 1);
                int pix = (yl + ky) * PW + xl + kx;
                int aoff = pix * 32 + (((quad + (pix >> 1)) & 3) * 8);
                short8 ah = *(const short8*)&lA[0][aoff];
                short8 al = *(const short8*)&lA[1][aoff];
                #pragma unroll
                for (int nt = 0; nt < NT; ++nt) {
                    acc[mt][nt] = __builtin_amdgcn_mfma_f32_16x16x32_bf16(ah, bh[nt], acc[mt][nt], 0, 0, 0);
                    acc[mt][nt] = __builtin_amdgcn_mfma_f32_16x16x32_bf16(ah, bl[nt], acc[mt][nt], 0, 0, 0);
                    acc[mt][nt] = __builtin_amdgcn_mfma_f32_16x16x32_bf16(al, bh[nt], acc[mt][nt], 0, 0, 0);
                }
            }
        }
    }

    if constexpr (MODE == 0) {
        #pragma unroll
        for (int mt = 0; mt < 4; ++mt) {
            int pbase = wm * 64 + mt * 16 + quad * 4;
            int yy = pbase >> LW2;
            #pragma unroll
            for (int nt = 0; nt < NT; ++nt) {
                int n = nblk * BN + wn * (NT * 16) + nt * 16 + l15;
                float bs = bias[n];
                #pragma unroll
                for (int r = 0; r < 4; ++r) {
                    int xx = (pbase & (W - 1)) + r;
                    float v = acc[mt][nt][r] + bs; v = v > 0.f ? v : 0.f;
                    size_t oo = ((size_t)(img * (H + 2) + y0 + yy + 1) * (W + 2) + xx + 1) * COUT + n;
                    u16 hh = f2bf(v);
                    Oh[oo] = hh;
                    Ol[oo] = f2bf(v - bf2f(hh));
                }
            }
        }
    } else if constexpr (MODE == 1) {
        // conv1: WN=1 (wn=0), NT=4 — identical to R6
        #pragma unroll
        for (int nt = 0; nt < NT; ++nt) {
            int n = nt * 16 + l15;
            float bs = bias[n];
            #pragma unroll
            for (int mb = 0; mb < 2; ++mb) {
                #pragma unroll
                for (int xp = 0; xp < 2; ++xp) {
                    float v = fmaxf(fmaxf(acc[mb][nt][2 * xp], acc[mb][nt][2 * xp + 1]),
                                    fmaxf(acc[mb + 2][nt][2 * xp], acc[mb + 2][nt][2 * xp + 1]));
                    v += bs; v = v > 0.f ? v : 0.f;
                    int py = (y0 >> 1) + wm;
                    int px = mb * 8 + quad * 2 + xp;
                    size_t oo = ((size_t)(img * 18 + py + 1) * 18 + px + 1) * COUT + n;
                    u16 hh = f2bf(v);
                    Oh[oo] = hh;
                    Ol[oo] = f2bf(v - bf2f(hh));
                }
            }
        }
    } else {
        __shared__ float fbuf[2][BN];
        #pragma unroll
        for (int nt = 0; nt < NT; ++nt) {
            int col = wn * (NT * 16) + nt * 16 + l15;       // 0..BN-1
            float bs = bias[nblk * BN + col];
            float s = 0.f;
            #pragma unroll
            for (int mp = 0; mp < 2; ++mp)
              #pragma unroll
              for (int xp = 0; xp < 2; ++xp) {
                  float v = fmaxf(fmaxf(acc[2 * mp][nt][2 * xp], acc[2 * mp][nt][2 * xp + 1]),
                                  fmaxf(acc[2 * mp + 1][nt][2 * xp], acc[2 * mp + 1][nt][2 * xp + 1]));
                  v += bs; v = v > 0.f ? v : 0.f;
                  s += v;
              }
            s += __shfl_xor(s, 16, 64);
            s += __shfl_xor(s, 32, 64);
            if (quad == 0) fbuf[wm][col] = s;
        }
        __syncthreads();
        if (tid < BN) {
            float f = (fbuf[0][tid] + fbuf[1][tid]) * (1.0f / 64.0f);
            featsPart[((size_t)(mblk % MPI) * 512 + img) * 256 + nblk * BN + tid] = f;
        }
    }
}

// ============== head GEMM + log-softmax + conf ==============
__global__ __launch_bounds__(128) void head_kernel(
    const float* __restrict__ featsPart, const float* __restrict__ cls_w,
    const float* __restrict__ cls_b, float* __restrict__ logits,
    float* __restrict__ conf)
{
    __shared__ float f[256];
    __shared__ float wt[80 * 65];
    __shared__ float lg[80];
    const int b = blockIdx.x, tid = (int)threadIdx.x;
    f[tid]       = featsPart[b * 256 + tid]       + featsPart[131072 + b * 256 + tid];
    f[tid + 128] = featsPart[b * 256 + tid + 128] + featsPart[131072 + b * 256 + tid + 128];
    float acc = 0.f;
    for (int ch = 0; ch < 4; ++ch) {
        __syncthreads();
        for (int q = tid; q < 80 * 64; q += 128) {
            int r = q >> 6, cc = q & 63;
            wt[r * 65 + cc] = cls_w[r * 256 + ch * 64 + cc];
        }
        __syncthreads();
        if (tid < 80) {
            #pragma unroll 8
            for (int dd = 0; dd < 64; ++dd)
                acc += wt[tid * 65 + dd] * f[ch * 64 + dd];
        }
    }
    if (tid < 80) {
        acc += cls_b[tid];
        logits[b * 80 + tid] = acc;
        lg[tid] = acc;
    }
    __syncthreads();
    if (tid < 80 && (tid % 10) == 0) {
        const int e = tid / 10;
        float m = lg[e * 10];
        for (int cc = 1; cc < 10; ++cc) m = fmaxf(m, lg[e * 10 + cc]);
        float ssum = 0.f;
        for (int cc = 0; cc < 10; ++cc) ssum += expf(lg[e * 10 + cc] - m);
        float lz = m + logf(ssum);
        float cf = 0.f;
        for (int cc = 0; cc < 10; ++cc) {
            float lp = lg[e * 10 + cc] - lz;
            cf += expf(lp) * lp;
        }
        conf[b * 8 + e] = cf;
    }
}

// ======= presort: per-expert descending sort of conf (done ONCE) =======
__global__ __launch_bounds__(256) void presort_kernel(
    const float* __restrict__ confG, u16* __restrict__ sidx0)
{
    __shared__ float v[512];
    __shared__ u16 bi[512];
    const int j = (int)blockIdx.x, tid = (int)threadIdx.x;
    for (int r = tid; r < 512; r += 256) { v[r] = confG[r * 8 + j]; bi[r] = (u16)r; }
    for (int k = 2; k <= 512; k <<= 1)
        for (int jj = k >> 1; jj > 0; jj >>= 1) {
            __syncthreads();
            int i = ((tid & ~(jj - 1)) << 1) | (tid & (jj - 1));
            int p = i | jj;
            float va = v[i], vb = v[p];
            u16 ia = bi[i], ib = bi[p];
            bool first = (va > vb) || (va == vb && ia < ib);
            bool up = (i & k) == 0;
            if (up ? !first : first) { v[i] = vb; v[p] = va; bi[i] = ib; bi[p] = ia; }
        }
    __syncthreads();
    for (int r = tid; r < 512; r += 256)
        sidx0[j * 512 + r] = (u16)(bi[r] * 8 + j);
}

// ======= routing: per cycle [rescale -> 3-level merge-path -> greedy scan] + final =======
__global__ __launch_bounds__(1024) void route_kernel(
    const float* __restrict__ confG,   // [512*8]
    const float* __restrict__ logitsG, // [512*80]
    const u16*   __restrict__ sidx0,   // [4096] presorted per-expert idx lists
    float* __restrict__ outv)          // [5120 final | 4096 conf | 4096 D]
{
    __shared__ float valById[4096];
    __shared__ float sv[4096];
    __shared__ u16 P[4096];
    __shared__ u16 mA[4096];
    __shared__ u16 mB[4096];
    __shared__ unsigned char Dls[512];
    __shared__ int ec[8];
    __shared__ int assignedS;
    const int tid = (int)threadIdx.x;

    for (int t = tid; t < 4096; t += 1024) {
        valById[t] = confG[t];
        P[t] = sidx0[t];
    }
    if (tid < 512) Dls[tid] = 0;
    if (tid < 8) ec[tid] = 0;
    if (tid == 0) assignedS = 0;

    auto earlier = [&](u16 a, u16 b) -> bool {
        float va = sv[a], vb = sv[b];
        return (va > vb) || (va == vb && a < b);
    };
    auto mergeChunk = [&](const u16* X, const u16* Y, int n, int o0, u16* out) {
        int lo = o0 - n; if (lo < 0) lo = 0;
        int hi = o0 < n ? o0 : n;
        while (lo < hi) {
            int mid = (lo + hi) >> 1;
            if (earlier(X[mid], Y[o0 - 1 - mid])) lo = mid + 1; else hi = mid;
        }
        int i = lo, jj = o0 - lo;
        #pragma unroll
        for (int q = 0; q < 4; ++q) {
            u16 xc = X[i < n ? i : (n - 1)];
            u16 yc = Y[jj < n ? jj : (n - 1)];
            bool takeX = (jj >= n) || ((i < n) && earlier(xc, yc));
            out[q] = takeX ? xc : yc;
            if (takeX) ++i; else ++jj;
        }
    };

    for (int cycle = 0; cycle < 4; ++cycle) {
        __syncthreads();
        for (int t = tid; t < 4096; t += 1024) {
            float sc = 1.0f - ((float)ec[t & 7]) / 160.0f;
            sv[t] = valById[t] * sc;
        }
        __syncthreads();
        {   // L1: P (8 lists of 512) -> mA (4 lists of 1024)
            int g = tid << 2;
            int p = g >> 10, o0 = g & 1023;
            mergeChunk(&P[(p << 1) * 512], &P[(p << 1) * 512 + 512], 512, o0, &mA[(p << 10) + o0]);
        }
        __syncthreads();
        {   // L2: mA -> mB (2 lists of 2048)
            int g = tid << 2;
            int p = g >> 11, o0 = g & 2047;
            mergeChunk(&mA[p << 11], &mA[(p << 11) + 1024], 1024, o0, &mB[(p << 11) + o0]);
        }
        __syncthreads();
        {   // L3: mB -> mA (full 4096 order, descending)
            int o0 = tid << 2;
            mergeChunk(&mB[0], &mB[2048], 2048, o0, &mA[o0]);
        }
        __syncthreads();
        if (tid < 64) {
            const int lane = tid;
            int cyc = 0;
            int assigned = assignedS;
            for (int chunk = 0; chunk < 64; ++chunk) {
                if (cyc >= 256 || assigned >= 1024) break;
                int id = mA[(chunk << 6) | lane];
                int b = id >> 3, j = id & 7;
                unsigned d = Dls[b];
                bool notA = ((d >> j) & 1) == 0;
                int ecj = ec[j];
                int scb = __popc(d & 255);
                unsigned long long sb = ~0ull;
                #pragma unroll
                for (int t2 = 0; t2 < 9; ++t2) {
                    unsigned long long bl = __ballot((b >> t2) & 1);
                    sb &= ((b >> t2) & 1) ? bl : ~bl;
                }
                unsigned long long jb0 = __ballot(j & 1);
                unsigned long long jb1 = __ballot((j >> 1) & 1);
                unsigned long long jb2 = __ballot((j >> 2) & 1);
                unsigned long long sj = ((j & 1) ? jb0 : ~jb0) &
                                        ((j & 2) ? jb1 : ~jb1) &
                                        ((j & 4) ? jb2 : ~jb2);
                unsigned long long earlierM = (1ull << lane) - 1ull;
                bool ok = notA && (ecj < 160) && (scb < 2);
                unsigned long long okm = __ballot(ok);
                for (int it = 0; it < 64; ++it) {
                    unsigned long long em = okm & earlierM;
                    int aE = __popcll(em & sj);
                    int aS = __popcll(em & sb);
                    int aC = __popcll(em);
                    bool ok2 = notA && (ecj + aE) < 160 && (scb + aS) < 2 &&
                               (cyc + aC) < 256 && (assigned + aC) < 1024;
                    unsigned long long okm2 = __ballot(ok2);
                    ok = ok2;
                    if (okm2 == okm) break;
                    okm = okm2;
                }
                int add = __popcll(okm);
                if (lane < 8) {
                    unsigned long long mj = ((lane & 1) ? jb0 : ~jb0) &
                                            ((lane & 2) ? jb1 : ~jb1) &
                                            ((lane & 4) ? jb2 : ~jb2);
                    int c2 = __popcll(mj & okm);
                    if (c2) ec[lane] += c2;
                }
                if (ok) {
                    unsigned long long grp = okm & sb;
                    if (lane == __builtin_ctzll(grp)) {
                        unsigned orb = 0;
                        #pragma unroll
                        for (int jj2 = 0; jj2 < 8; ++jj2) {
                            unsigned long long mj2 = ((jj2 & 1) ? jb0 : ~jb0) &
                                                     ((jj2 & 2) ? jb1 : ~jb1) &
                                                     ((jj2 & 4) ? jb2 : ~jb2);
                            if (mj2 & grp) orb |= (1u << jj2);
                        }
                        Dls[b] = (unsigned char)(d | orb);
                    }
                }
                cyc += add;
                assigned += add;
                __threadfence_block();
            }
            if (lane == 0) assignedS = assigned;
        }
    }
    __syncthreads();

    for (int o = tid; o < 5120; o += 1024) {
        int b = o / 10, c = o - b * 10;
        unsigned d = Dls[b];
        float norm = fmaxf((float)__popc(d & 255), 1.0f);
        float sum = 0.f;
        #pragma unroll
        for (int e = 0; e < 8; ++e)
            if ((d >> e) & 1)
                sum += confG[b * 8 + e] * logitsG[(b * 8 + e) * 10 + c];
        outv[o] = sum / norm;
    }
    for (int t = tid; t < 4096; t += 1024) {
        outv[5120 + t] = confG[t];
        outv[9216 + t] = (float)((Dls[t >> 3] >> (t & 7)) & 1);
    }
}

// ============================ launch ============================
extern "C" void kernel_launch(void* const* d_in, const int* in_sizes, int n_in,
                              void* d_out, int out_size, void* d_ws, size_t ws_size,
                              hipStream_t stream)
{
    const float* x    = (const float*)d_in[0];
    const float* w0   = (const float*)d_in[1];
    const float* b0   = (const float*)d_in[2];
    const float* g0   = (const float*)d_in[3];
    const float* bt0  = (const float*)d_in[4];
    const float* rm0  = (const float*)d_in[5];
    const float* rv0  = (const float*)d_in[6];
    const float* w1   = (const float*)d_in[7];
    const float* b1   = (const float*)d_in[8];
    const float* g1   = (const float*)d_in[9];
    const float* bt1  = (const float*)d_in[10];
    const float* rm1  = (const float*)d_in[11];
    const float* rv1  = (const float*)d_in[12];
    const float* w2   = (const float*)d_in[13];
    const float* b2   = (const float*)d_in[14];
    const float* g2   = (const float*)d_in[15];
    const float* bt2  = (const float*)d_in[16];
    const float* rm2  = (const float*)d_in[17];
    const float* rv2  = (const float*)d_in[18];
    const float* w3   = (const float*)d_in[19];
    const float* b3   = (const float*)d_in[20];
    const float* g3   = (const float*)d_in[21];
    const float* bt3  = (const float*)d_in[22];
    const float* rm3  = (const float*)d_in[23];
    const float* rv3  = (const float*)d_in[24];
    const float* cls_w = (const float*)d_in[25];
    const float* cls_b = (const float*)d_in[26];
    float* outp = (float*)d_out;

    char* ws = (char*)d_ws;
    u16* A1H = (u16*)(ws);
    u16* A1L = (u16*)(ws + 21233664);
    u16* A0H = (u16*)(ws + 42467328);
    u16* A0L = (u16*)(ws + 42467328 + 37879808);
    u16* A2H = (u16*)(ws + 42467328);
    u16* A2L = (u16*)(ws + 42467328 + 42467328);
    u16* W1H = (u16*)(ws + 127401984);
    u16* W1L = (u16*)(ws + 127438848);
    u16* W2H = (u16*)(ws + 127475712);
    u16* W2L = (u16*)(ws + 127623168);
    u16* W3H = (u16*)(ws + 127770624);
    u16* W3L = (u16*)(ws + 128360448);
    float* BS1 = (float*)(ws + 128950272);
    float* BS2 = (float*)(ws + 128950528);
    float* BS3 = (float*)(ws + 128951040);
    float* featsPart = (float*)(ws + 128952064);   // [2][512][256]
    float* logits    = (float*)(ws + 130000640);
    float* conf      = (float*)(ws + 130164480);
    u16* sidx0 = (u16*)(ws + 42467328);            // dead-after-conv3 region

    ring_kernel<34, 34, 32><<<(512 * 132 * 4 + 255) / 256, 256, 0, stream>>>(A0H, A0L);
    ring_kernel<18, 18, 64><<<(512 * 68 * 8 + 255) / 256, 256, 0, stream>>>(A1H, A1L);
    wprep_kernel<32, 64><<<8, 256, 0, stream>>>(w1, b1, g1, bt1, rm1, rv1, W1H, W1L, BS1);
    wprep_kernel<64, 128><<<32, 256, 0, stream>>>(w2, b2, g2, bt2, rm2, rv2, W2H, W2L, BS2);
    wprep_kernel<128, 256><<<128, 256, 0, stream>>>(w3, b3, g3, bt3, rm3, rv3, W3H, W3L, BS3);

    conv0_kernel<<<2048, 256, 0, stream>>>(x, w0, b0, g0, bt0, rm0, rv0, A0H, A0L);
    convM_kernel<32, 64, 32, 32, 256, 64, 1>
        <<<dim3(2048, 1), 256, 0, stream>>>(A0H, A0L, W1H, W1L, BS1, A1H, A1L, nullptr);
    ring_kernel<18, 18, 128><<<(512 * 68 * 16 + 255) / 256, 256, 0, stream>>>(A2H, A2L);
    convM_kernel<64, 128, 16, 16, 128, 64, 0>
        <<<dim3(1024, 2), 256, 0, stream>>>(A1H, A1L, W2H, W2L, BS2, A2H, A2L, nullptr);
    convM_kernel<128, 256, 16, 16, 128, 64, 2>
        <<<dim3(1024, 4), 256, 0, stream>>>(A2H, A2L, W3H, W3L, BS3, nullptr, nullptr, featsPart);
    head_kernel<<<512, 128, 0, stream>>>(featsPart, cls_w, cls_b, logits, conf);
    presort_kernel<<<8, 256, 0, stream>>>(conf, sidx0);
    route_kernel<<<1, 1024, 0, stream>>>(conf, logits, sidx0, outp);
}

// Round 11
// 610.876 us; speedup vs baseline: 1.4353x; 1.0203x over previous
//
#include <hip/hip_runtime.h>
#include <hip/hip_bf16.h>
#include <cstdint>
#include <cstddef>

#define EPSV 1e-5f
typedef unsigned short u16;
using short8 = __attribute__((ext_vector_type(8))) short;
using f32x4  = __attribute__((ext_vector_type(4))) float;

typedef __attribute__((address_space(1))) void* gp1;
typedef __attribute__((address_space(3))) void* lp3;

__device__ __forceinline__ void gload16(const void* g, void* l) {
    __builtin_amdgcn_global_load_lds((gp1)(void*)g, (lp3)l, 16, 0, 0);
}
__device__ __forceinline__ u16 f2bf(float v) {
    __hip_bfloat16 h = __float2bfloat16(v);
    return *reinterpret_cast<u16*>(&h);
}
__device__ __forceinline__ float bf2f(u16 u) {
    __hip_bfloat16 h; *reinterpret_cast<u16*>(&h) = u;
    return __bfloat162float(h);
}

// ============ ring zero: zero the 1-px border of padded NHWC bf16 planes ============
template<int PH2, int PW2, int C>
__global__ __launch_bounds__(256) void ring_kernel(u16* __restrict__ bh, u16* __restrict__ bl)
{
    constexpr int RN = 2 * PW2 + 2 * (PH2 - 2);
    constexpr int C8 = C / 8;
    int id = blockIdx.x * 256 + (int)threadIdx.x;
    if (id >= 512 * RN * C8) return;
    int c8 = id % C8; int t = id / C8;
    int rp = t % RN;  int im = t / RN;
    int py, px;
    if (rp < PW2)            { py = 0;       px = rp; }
    else if (rp < 2 * PW2)   { py = PH2 - 1; px = rp - PW2; }
    else { int rr = rp - 2 * PW2; py = 1 + (rr >> 1); px = (rr & 1) ? (PW2 - 1) : 0; }
    size_t off = ((size_t)(im * PH2 + py) * PW2 + px) * C + c8 * 8;
    uint4 z = {0u, 0u, 0u, 0u};
    *(uint4*)(bh + off) = z;
    *(uint4*)(bl + off) = z;
}

// ============ weight prep: fold BN scale, transpose to [9][Cout][Cin], split bf16 ============
template<int CIN, int COUT>
__global__ __launch_bounds__(256) void wprep_kernel(
    const float* __restrict__ w, const float* __restrict__ b,
    const float* __restrict__ g, const float* __restrict__ bt,
    const float* __restrict__ rm, const float* __restrict__ rv,
    u16* __restrict__ WH, u16* __restrict__ WL, float* __restrict__ bias)
{
    int id = blockIdx.x * 256 + (int)threadIdx.x;
    if (id >= CIN * COUT) return;
    int co = id / CIN, ci = id % CIN;
    float s = g[co] / sqrtf(rv[co] + EPSV);
    #pragma unroll
    for (int k = 0; k < 9; ++k) {
        float v = w[((size_t)co * CIN + ci) * 9 + k] * s;
        u16 hh = f2bf(v);
        size_t o = ((size_t)k * COUT + co) * CIN + ci;
        WH[o] = hh;
        WL[o] = f2bf(v - bf2f(hh));
    }
    if (ci == 0) bias[co] = (b[co] - rm[co]) * s + bt[co];
}

// ============ conv0: 3->32, fp32 vector math, out = padded NHWC split-bf16 ============
__global__ __launch_bounds__(256) void conv0_kernel(
    const float* __restrict__ x, const float* __restrict__ w,
    const float* __restrict__ bias, const float* __restrict__ g,
    const float* __restrict__ bt, const float* __restrict__ rm,
    const float* __restrict__ rv, u16* __restrict__ Oh, u16* __restrict__ Ol)
{
    const int blk = blockIdx.x;            // 2048 blocks
    const int img = blk >> 2;
    const int p = ((blk & 3) << 8) | (int)threadIdx.x;   // pixel 0..1023
    const int y = p >> 5, xx = p & 31;
    const float* xin = x + (size_t)img * 3 * 1024;
    float xv[3][9];
    #pragma unroll
    for (int ci = 0; ci < 3; ++ci)
      #pragma unroll
      for (int ky = 0; ky < 3; ++ky)
        #pragma unroll
        for (int kx = 0; kx < 3; ++kx) {
            int yy = y + ky - 1, xc = xx + kx - 1;
            bool v = (yy >= 0) && (yy < 32) && (xc >= 0) && (xc < 32);
            xv[ci][ky * 3 + kx] = v ? xin[ci * 1024 + yy * 32 + xc] : 0.0f;
        }
    union { u16 u[32]; uint4 v4[4]; } oh, ol;
    #pragma unroll
    for (int co = 0; co < 32; ++co) {
        float s = g[co] / sqrtf(rv[co] + EPSV);
        float c = (bias[co] - rm[co]) * s + bt[co];
        float acc = 0.f;
        #pragma unroll
        for (int ci = 0; ci < 3; ++ci)
          #pragma unroll
          for (int k = 0; k < 9; ++k)
            acc += w[(co * 3 + ci) * 9 + k] * xv[ci][k];
        float v = acc * s + c;
        v = v > 0.f ? v : 0.f;
        u16 hh = f2bf(v);
        oh.u[co] = hh;
        ol.u[co] = f2bf(v - bf2f(hh));
    }
    size_t po = ((size_t)(img * 34 + y + 1) * 34 + xx + 1) * 32;
    #pragma unroll
    for (int q = 0; q < 4; ++q) {
        ((uint4*)(Oh + po))[q] = oh.v4[q];
        ((uint4*)(Ol + po))[q] = ol.v4[q];
    }
}

// ============ MFMA conv: shift-and-GEMM, split-bf16, padded NHWC in/out ============
// R11: ky-grouped B staging. Per cb: stage A once; per ky (3): stage the 3 kx
// B-tiles at once (lB=[2][3*BN*32]); inner kx loop is barrier-free. Barriers
// per cb: 20 -> 6 (the R6/R10 profiles cap at MfmaUtil ~54% with LDS-port and
// barrier drains sharing the blame; this removes 70% of the drains at zero
// cost in LDS reads/MFMA). Swizzle kept (conflicts=0). conv2 back to BN=128
// (R6-proven; R10's BN=64 split regressed conv2 ~20us via 2x A1 re-fetch).
template<int CIN, int COUT, int H, int W, int BM, int BN, int MODE>
__global__ __launch_bounds__(256, 2) void convM_kernel(
    const u16* __restrict__ Ah, const u16* __restrict__ Al,
    const u16* __restrict__ Wh, const u16* __restrict__ Wl,
    const float* __restrict__ bias,
    u16* __restrict__ Oh, u16* __restrict__ Ol, float* __restrict__ featsPart)
{
    constexpr int KC = CIN / 32;
    constexpr int ROWS = BM / W;
    constexpr int WM = BM / 64;             // wave-m groups (4 or 2)
    constexpr int WN = 4 / WM;              // wave-n groups (1 or 2)
    constexpr int NT = BN / (WN * 16);      // 16-wide n-frags per wave
    constexpr int PW = W + 2;
    constexpr int AT = (ROWS + 2) * PW;
    constexpr int ACH = AT * 4;
    constexpr int BCH3 = 3 * BN * 4;        // 16B chunks per 3-tap B group (per plane)
    constexpr int LW2 = (W == 32) ? 5 : 4;
    constexpr int MPI = (H * W) / BM;

    __shared__ u16 lA[2][AT * 32];
    __shared__ u16 lB[2][3 * BN * 32];      // [plane][kx][n][32ci], swizzled per n

    const int tid = (int)threadIdx.x;
    const int lane = tid & 63;
    const int wv = tid >> 6;
    const int wm = (WM == 4) ? wv : (wv >> 1);
    const int wn = (WM == 4) ? 0 : (wv & 1);
    const int l15 = lane & 15, quad = lane >> 4;

    const int mblk = (int)blockIdx.x, nblk = (int)blockIdx.y;
    const int img = mblk / MPI;
    const int y0 = (mblk % MPI) * ROWS;
    const size_t imgRow = (size_t)img * (H + 2);

    f32x4 acc[4][NT];
    f32x4 zz = {0.f, 0.f, 0.f, 0.f};
    #pragma unroll
    for (int i = 0; i < 4; ++i)
      #pragma unroll
      for (int j = 0; j < NT; ++j) acc[i][j] = zz;

    // A staging (swizzle: 16B chunk q of 64B line p at slot (q+(p>>1))&3)
    auto stageA = [&](int cb) {
        #pragma unroll
        for (int it = 0; it < (ACH + 255) / 256; ++it) {
            int id = it * 256 + tid;
            if (id < ACH) {
                int p = id >> 2;
                int s = ((id & 3) - (p >> 1)) & 3;
                int yy = p / PW, xx = p - yy * PW;
                size_t ge = ((imgRow + y0 + yy) * PW + xx) * CIN + cb * 32 + s * 8;
                u16* ld = (u16*)&lA[0][0] + (size_t)(it * 256 + wv * 64) * 8;
                gload16(Ah + ge, ld);
                gload16(Al + ge, ld + AT * 32);
            }
        }
    };
    // B staging: all 3 kx taps of one ky (chunk id = kx*BN*4 + n*4 + slot)
    auto stageB3 = [&](int cb, int ky) {
        #pragma unroll
        for (int it = 0; it < (BCH3 + 255) / 256; ++it) {
            int id = it * 256 + tid;
            if (id < BCH3) {
                int kx = id / (BN * 4);
                int r = id - kx * (BN * 4);
                int n = r >> 2;
                int s = ((r & 3) - (n >> 1)) & 3;
                size_t ge = ((size_t)(ky * 3 + kx) * COUT + nblk * BN + n) * CIN + cb * 32 + s * 8;
                u16* ld = (u16*)&lB[0][0] + (size_t)(it * 256 + wv * 64) * 8;
                gload16(Wh + ge, ld);
                gload16(Wl + ge, ld + 3 * BN * 32);
            }
        }
    };

    for (int cb = 0; cb < KC; ++cb) {
        __syncthreads();                    // WAR: prev readers of lA/lB done
        stageA(cb);
        stageB3(cb, 0);
        __syncthreads();                    // staged A + B(ky=0) landed
        #pragma unroll
        for (int ky = 0; ky < 3; ++ky) {
            if (ky) {
                __syncthreads();            // WAR: readers of lB(ky-1) done
                stageB3(cb, ky);
                __syncthreads();            // B(ky) landed
            }
            #pragma unroll
            for (int kx = 0; kx < 3; ++kx) {
                short8 bh[NT], bl[NT];
                #pragma unroll
                for (int nt = 0; nt < NT; ++nt) {
                    int nrow = wn * (NT * 16) + nt * 16 + l15;
                    int boff = kx * BN * 32 + nrow * 32 + (((quad + (nrow >> 1)) & 3) * 8);
                    bh[nt] = *(const short8*)&lB[0][boff];
                    bl[nt] = *(const short8*)&lB[1][boff];
                }
                #pragma unroll
                for (int mt = 0; mt < 4; ++mt) {
                    int p = wm * 64 + mt * 16 + l15;
                    int yl = p >> LW2, xl = p & (W - 1);
                    int pix = (yl + ky) * PW + xl + kx;
                    int aoff = pix * 32 + (((quad + (pix >> 1)) & 3) * 8);
                    short8 ah = *(const short8*)&lA[0][aoff];
                    short8 al = *(const short8*)&lA[1][aoff];
                    #pragma unroll
                    for (int nt = 0; nt < NT; ++nt) {
                        acc[mt][nt] = __builtin_amdgcn_mfma_f32_16x16x32_bf16(ah, bh[nt], acc[mt][nt], 0, 0, 0);
                        acc[mt][nt] = __builtin_amdgcn_mfma_f32_16x16x32_bf16(ah, bl[nt], acc[mt][nt], 0, 0, 0);
                        acc[mt][nt] = __builtin_amdgcn_mfma_f32_16x16x32_bf16(al, bh[nt], acc[mt][nt], 0, 0, 0);
                    }
                }
            }
        }
    }

    if constexpr (MODE == 0) {
        #pragma unroll
        for (int mt = 0; mt < 4; ++mt) {
            int pbase = wm * 64 + mt * 16 + quad * 4;
            int yy = pbase >> LW2;
            #pragma unroll
            for (int nt = 0; nt < NT; ++nt) {
                int n = nblk * BN + wn * (NT * 16) + nt * 16 + l15;
                float bs = bias[n];
                #pragma unroll
                for (int r = 0; r < 4; ++r) {
                    int xx = (pbase & (W - 1)) + r;
                    float v = acc[mt][nt][r] + bs; v = v > 0.f ? v : 0.f;
                    size_t oo = ((size_t)(img * (H + 2) + y0 + yy + 1) * (W + 2) + xx + 1) * COUT + n;
                    u16 hh = f2bf(v);
                    Oh[oo] = hh;
                    Ol[oo] = f2bf(v - bf2f(hh));
                }
            }
        }
    } else if constexpr (MODE == 1) {
        // conv1: WN=1 (wn=0), NT=4
        #pragma unroll
        for (int nt = 0; nt < NT; ++nt) {
            int n = nt * 16 + l15;
            float bs = bias[n];
            #pragma unroll
            for (int mb = 0; mb < 2; ++mb) {
                #pragma unroll
                for (int xp = 0; xp < 2; ++xp) {
                    float v = fmaxf(fmaxf(acc[mb][nt][2 * xp], acc[mb][nt][2 * xp + 1]),
                                    fmaxf(acc[mb + 2][nt][2 * xp], acc[mb + 2][nt][2 * xp + 1]));
                    v += bs; v = v > 0.f ? v : 0.f;
                    int py = (y0 >> 1) + wm;
                    int px = mb * 8 + quad * 2 + xp;
                    size_t oo = ((size_t)(img * 18 + py + 1) * 18 + px + 1) * COUT + n;
                    u16 hh = f2bf(v);
                    Oh[oo] = hh;
                    Ol[oo] = f2bf(v - bf2f(hh));
                }
            }
        }
    } else {
        __shared__ float fbuf[2][BN];
        #pragma unroll
        for (int nt = 0; nt < NT; ++nt) {
            int col = wn * (NT * 16) + nt * 16 + l15;       // 0..BN-1
            float bs = bias[nblk * BN + col];
            float s = 0.f;
            #pragma unroll
            for (int mp = 0; mp < 2; ++mp)
              #pragma unroll
              for (int xp = 0; xp < 2; ++xp) {
                  float v = fmaxf(fmaxf(acc[2 * mp][nt][2 * xp], acc[2 * mp][nt][2 * xp + 1]),
                                  fmaxf(acc[2 * mp + 1][nt][2 * xp], acc[2 * mp + 1][nt][2 * xp + 1]));
                  v += bs; v = v > 0.f ? v : 0.f;
                  s += v;
              }
            s += __shfl_xor(s, 16, 64);
            s += __shfl_xor(s, 32, 64);
            if (quad == 0) fbuf[wm][col] = s;
        }
        __syncthreads();
        if (tid < BN) {
            float f = (fbuf[0][tid] + fbuf[1][tid]) * (1.0f / 64.0f);
            featsPart[((size_t)(mblk % MPI) * 512 + img) * 256 + nblk * BN + tid] = f;
        }
    }
}

// ============== head GEMM + log-softmax + conf ==============
__global__ __launch_bounds__(128) void head_kernel(
    const float* __restrict__ featsPart, const float* __restrict__ cls_w,
    const float* __restrict__ cls_b, float* __restrict__ logits,
    float* __restrict__ conf)
{
    __shared__ float f[256];
    __shared__ float wt[80 * 65];
    __shared__ float lg[80];
    const int b = blockIdx.x, tid = (int)threadIdx.x;
    f[tid]       = featsPart[b * 256 + tid]       + featsPart[131072 + b * 256 + tid];
    f[tid + 128] = featsPart[b * 256 + tid + 128] + featsPart[131072 + b * 256 + tid + 128];
    float acc = 0.f;
    for (int ch = 0; ch < 4; ++ch) {
        __syncthreads();
        for (int q = tid; q < 80 * 64; q += 128) {
            int r = q >> 6, cc = q & 63;
            wt[r * 65 + cc] = cls_w[r * 256 + ch * 64 + cc];
        }
        __syncthreads();
        if (tid < 80) {
            #pragma unroll 8
            for (int dd = 0; dd < 64; ++dd)
                acc += wt[tid * 65 + dd] * f[ch * 64 + dd];
        }
    }
    if (tid < 80) {
        acc += cls_b[tid];
        logits[b * 80 + tid] = acc;
        lg[tid] = acc;
    }
    __syncthreads();
    if (tid < 80 && (tid % 10) == 0) {
        const int e = tid / 10;
        float m = lg[e * 10];
        for (int cc = 1; cc < 10; ++cc) m = fmaxf(m, lg[e * 10 + cc]);
        float ssum = 0.f;
        for (int cc = 0; cc < 10; ++cc) ssum += expf(lg[e * 10 + cc] - m);
        float lz = m + logf(ssum);
        float cf = 0.f;
        for (int cc = 0; cc < 10; ++cc) {
            float lp = lg[e * 10 + cc] - lz;
            cf += expf(lp) * lp;
        }
        conf[b * 8 + e] = cf;
    }
}

// ======= presort: per-expert descending sort of conf (done ONCE) =======
__global__ __launch_bounds__(256) void presort_kernel(
    const float* __restrict__ confG, u16* __restrict__ sidx0)
{
    __shared__ float v[512];
    __shared__ u16 bi[512];
    const int j = (int)blockIdx.x, tid = (int)threadIdx.x;
    for (int r = tid; r < 512; r += 256) { v[r] = confG[r * 8 + j]; bi[r] = (u16)r; }
    for (int k = 2; k <= 512; k <<= 1)
        for (int jj = k >> 1; jj > 0; jj >>= 1) {
            __syncthreads();
            int i = ((tid & ~(jj - 1)) << 1) | (tid & (jj - 1));
            int p = i | jj;
            float va = v[i], vb = v[p];
            u16 ia = bi[i], ib = bi[p];
            bool first = (va > vb) || (va == vb && ia < ib);
            bool up = (i & k) == 0;
            if (up ? !first : first) { v[i] = vb; v[p] = va; bi[i] = ib; bi[p] = ia; }
        }
    __syncthreads();
    for (int r = tid; r < 512; r += 256)
        sidx0[j * 512 + r] = (u16)(bi[r] * 8 + j);
}

// ======= routing: per cycle [rescale -> 3-level merge-path -> greedy scan] + final =======
__global__ __launch_bounds__(1024) void route_kernel(
    const float* __restrict__ confG,   // [512*8]
    const float* __restrict__ logitsG, // [512*80]
    const u16*   __restrict__ sidx0,   // [4096] presorted per-expert idx lists
    float* __restrict__ outv)          // [5120 final | 4096 conf | 4096 D]
{
    __shared__ float valById[4096];
    __shared__ float sv[4096];
    __shared__ u16 P[4096];
    __shared__ u16 mA[4096];
    __shared__ u16 mB[4096];
    __shared__ unsigned char Dls[512];
    __shared__ int ec[8];
    __shared__ int assignedS;
    const int tid = (int)threadIdx.x;

    for (int t = tid; t < 4096; t += 1024) {
        valById[t] = confG[t];
        P[t] = sidx0[t];
    }
    if (tid < 512) Dls[tid] = 0;
    if (tid < 8) ec[tid] = 0;
    if (tid == 0) assignedS = 0;

    auto earlier = [&](u16 a, u16 b) -> bool {
        float va = sv[a], vb = sv[b];
        return (va > vb) || (va == vb && a < b);
    };
    auto mergeChunk = [&](const u16* X, const u16* Y, int n, int o0, u16* out) {
        int lo = o0 - n; if (lo < 0) lo = 0;
        int hi = o0 < n ? o0 : n;
        while (lo < hi) {
            int mid = (lo + hi) >> 1;
            if (earlier(X[mid], Y[o0 - 1 - mid])) lo = mid + 1; else hi = mid;
        }
        int i = lo, jj = o0 - lo;
        #pragma unroll
        for (int q = 0; q < 4; ++q) {
            u16 xc = X[i < n ? i : (n - 1)];
            u16 yc = Y[jj < n ? jj : (n - 1)];
            bool takeX = (jj >= n) || ((i < n) && earlier(xc, yc));
            out[q] = takeX ? xc : yc;
            if (takeX) ++i; else ++jj;
        }
    };

    for (int cycle = 0; cycle < 4; ++cycle) {
        __syncthreads();
        for (int t = tid; t < 4096; t += 1024) {
            float sc = 1.0f - ((float)ec[t & 7]) / 160.0f;
            sv[t] = valById[t] * sc;
        }
        __syncthreads();
        {   // L1: P (8 lists of 512) -> mA (4 lists of 1024)
            int g = tid << 2;
            int p = g >> 10, o0 = g & 1023;
            mergeChunk(&P[(p << 1) * 512], &P[(p << 1) * 512 + 512], 512, o0, &mA[(p << 10) + o0]);
        }
        __syncthreads();
        {   // L2: mA -> mB (2 lists of 2048)
            int g = tid << 2;
            int p = g >> 11, o0 = g & 2047;
            mergeChunk(&mA[p << 11], &mA[(p << 11) + 1024], 1024, o0, &mB[(p << 11) + o0]);
        }
        __syncthreads();
        {   // L3: mB -> mA (full 4096 order, descending)
            int o0 = tid << 2;
            mergeChunk(&mB[0], &mB[2048], 2048, o0, &mA[o0]);
        }
        __syncthreads();
        if (tid < 64) {
            const int lane = tid;
            int cyc = 0;
            int assigned = assignedS;
            for (int chunk = 0; chunk < 64; ++chunk) {
                if (cyc >= 256 || assigned >= 1024) break;
                int id = mA[(chunk << 6) | lane];
                int b = id >> 3, j = id & 7;
                unsigned d = Dls[b];
                bool notA = ((d >> j) & 1) == 0;
                int ecj = ec[j];
                int scb = __popc(d & 255);
                unsigned long long sb = ~0ull;
                #pragma unroll
                for (int t2 = 0; t2 < 9; ++t2) {
                    unsigned long long bl = __ballot((b >> t2) & 1);
                    sb &= ((b >> t2) & 1) ? bl : ~bl;
                }
                unsigned long long jb0 = __ballot(j & 1);
                unsigned long long jb1 = __ballot((j >> 1) & 1);
                unsigned long long jb2 = __ballot((j >> 2) & 1);
                unsigned long long sj = ((j & 1) ? jb0 : ~jb0) &
                                        ((j & 2) ? jb1 : ~jb1) &
                                        ((j & 4) ? jb2 : ~jb2);
                unsigned long long earlierM = (1ull << lane) - 1ull;
                bool ok = notA && (ecj < 160) && (scb < 2);
                unsigned long long okm = __ballot(ok);
                for (int it = 0; it < 64; ++it) {
                    unsigned long long em = okm & earlierM;
                    int aE = __popcll(em & sj);
                    int aS = __popcll(em & sb);
                    int aC = __popcll(em);
                    bool ok2 = notA && (ecj + aE) < 160 && (scb + aS) < 2 &&
                               (cyc + aC) < 256 && (assigned + aC) < 1024;
                    unsigned long long okm2 = __ballot(ok2);
                    ok = ok2;
                    if (okm2 == okm) break;
                    okm = okm2;
                }
                int add = __popcll(okm);
                if (lane < 8) {
                    unsigned long long mj = ((lane & 1) ? jb0 : ~jb0) &
                                            ((lane & 2) ? jb1 : ~jb1) &
                                            ((lane & 4) ? jb2 : ~jb2);
                    int c2 = __popcll(mj & okm);
                    if (c2) ec[lane] += c2;
                }
                if (ok) {
                    unsigned long long grp = okm & sb;
                    if (lane == __builtin_ctzll(grp)) {
                        unsigned orb = 0;
                        #pragma unroll
                        for (int jj2 = 0; jj2 < 8; ++jj2) {
                            unsigned long long mj2 = ((jj2 & 1) ? jb0 : ~jb0) &
                                                     ((jj2 & 2) ? jb1 : ~jb1) &
                                                     ((jj2 & 4) ? jb2 : ~jb2);
                            if (mj2 & grp) orb |= (1u << jj2);
                        }
                        Dls[b] = (unsigned char)(d | orb);
                    }
                }
                cyc += add;
                assigned += add;
                __threadfence_block();
            }
            if (lane == 0) assignedS = assigned;
        }
    }
    __syncthreads();

    for (int o = tid; o < 5120; o += 1024) {
        int b = o / 10, c = o - b * 10;
        unsigned d = Dls[b];
        float norm = fmaxf((float)__popc(d & 255), 1.0f);
        float sum = 0.f;
        #pragma unroll
        for (int e = 0; e < 8; ++e)
            if ((d >> e) & 1)
                sum += confG[b * 8 + e] * logitsG[(b * 8 + e) * 10 + c];
        outv[o] = sum / norm;
    }
    for (int t = tid; t < 4096; t += 1024) {
        outv[5120 + t] = confG[t];
        outv[9216 + t] = (float)((Dls[t >> 3] >> (t & 7)) & 1);
    }
}

// ============================ launch ============================
extern "C" void kernel_launch(void* const* d_in, const int* in_sizes, int n_in,
                              void* d_out, int out_size, void* d_ws, size_t ws_size,
                              hipStream_t stream)
{
    const float* x    = (const float*)d_in[0];
    const float* w0   = (const float*)d_in[1];
    const float* b0   = (const float*)d_in[2];
    const float* g0   = (const float*)d_in[3];
    const float* bt0  = (const float*)d_in[4];
    const float* rm0  = (const float*)d_in[5];
    const float* rv0  = (const float*)d_in[6];
    const float* w1   = (const float*)d_in[7];
    const float* b1   = (const float*)d_in[8];
    const float* g1   = (const float*)d_in[9];
    const float* bt1  = (const float*)d_in[10];
    const float* rm1  = (const float*)d_in[11];
    const float* rv1  = (const float*)d_in[12];
    const float* w2   = (const float*)d_in[13];
    const float* b2   = (const float*)d_in[14];
    const float* g2   = (const float*)d_in[15];
    const float* bt2  = (const float*)d_in[16];
    const float* rm2  = (const float*)d_in[17];
    const float* rv2  = (const float*)d_in[18];
    const float* w3   = (const float*)d_in[19];
    const float* b3   = (const float*)d_in[20];
    const float* g3   = (const float*)d_in[21];
    const float* bt3  = (const float*)d_in[22];
    const float* rm3  = (const float*)d_in[23];
    const float* rv3  = (const float*)d_in[24];
    const float* cls_w = (const float*)d_in[25];
    const float* cls_b = (const float*)d_in[26];
    float* outp = (float*)d_out;

    char* ws = (char*)d_ws;
    u16* A1H = (u16*)(ws);
    u16* A1L = (u16*)(ws + 21233664);
    u16* A0H = (u16*)(ws + 42467328);
    u16* A0L = (u16*)(ws + 42467328 + 37879808);
    u16* A2H = (u16*)(ws + 42467328);
    u16* A2L = (u16*)(ws + 42467328 + 42467328);
    u16* W1H = (u16*)(ws + 127401984);
    u16* W1L = (u16*)(ws + 127438848);
    u16* W2H = (u16*)(ws + 127475712);
    u16* W2L = (u16*)(ws + 127623168);
    u16* W3H = (u16*)(ws + 127770624);
    u16* W3L = (u16*)(ws + 128360448);
    float* BS1 = (float*)(ws + 128950272);
    float* BS2 = (float*)(ws + 128950528);
    float* BS3 = (float*)(ws + 128951040);
    float* featsPart = (float*)(ws + 128952064);   // [2][512][256]
    float* logits    = (float*)(ws + 130000640);
    float* conf      = (float*)(ws + 130164480);
    u16* sidx0 = (u16*)(ws + 42467328);            // dead-after-conv3 region

    ring_kernel<34, 34, 32><<<(512 * 132 * 4 + 255) / 256, 256, 0, stream>>>(A0H, A0L);
    ring_kernel<18, 18, 64><<<(512 * 68 * 8 + 255) / 256, 256, 0, stream>>>(A1H, A1L);
    wprep_kernel<32, 64><<<8, 256, 0, stream>>>(w1, b1, g1, bt1, rm1, rv1, W1H, W1L, BS1);
    wprep_kernel<64, 128><<<32, 256, 0, stream>>>(w2, b2, g2, bt2, rm2, rv2, W2H, W2L, BS2);
    wprep_kernel<128, 256><<<128, 256, 0, stream>>>(w3, b3, g3, bt3, rm3, rv3, W3H, W3L, BS3);

    conv0_kernel<<<2048, 256, 0, stream>>>(x, w0, b0, g0, bt0, rm0, rv0, A0H, A0L);
    convM_kernel<32, 64, 32, 32, 256, 64, 1>
        <<<dim3(2048, 1), 256, 0, stream>>>(A0H, A0L, W1H, W1L, BS1, A1H, A1L, nullptr);
    ring_kernel<18, 18, 128><<<(512 * 68 * 16 + 255) / 256, 256, 0, stream>>>(A2H, A2L);
    convM_kernel<64, 128, 16, 16, 128, 128, 0>
        <<<dim3(1024, 1), 256, 0, stream>>>(A1H, A1L, W2H, W2L, BS2, A2H, A2L, nullptr);
    convM_kernel<128, 256, 16, 16, 128, 64, 2>
        <<<dim3(1024, 4), 256, 0, stream>>>(A2H, A2L, W3H, W3L, BS3, nullptr, nullptr, featsPart);
    head_kernel<<<512, 128, 0, stream>>>(featsPart, cls_w, cls_b, logits, conf);
    presort_kernel<<<8, 256, 0, stream>>>(conf, sidx0);
    route_kernel<<<1, 1024, 0, stream>>>(conf, logits, sidx0, outp);
}